// Round 6
// baseline (87.614 us; speedup 1.0000x reference)
//
#include <hip/hip_runtime.h>
#include <math.h>

// Backflow: out[i] = xi(|x_i|,t)*x_i + sum_j eta(|x_i-x_j|,t)*(x_i-x_j)
// t scalar -> eta(r) is 1-D: dense table (513 pts over [0,16], linear interp)
// replaces 1M MLP evals. Fixed harness overhead ~72us (268MB ws re-poison
// @85% HBM + restore dispatches). Controllable: the single fused kernel.
//
// R8 FAILED (90.7): fence-heavy handshake (wbl2 + per-poll buffer_inv).
// R9 (86.8): relaxed sc1 handshake (zero cache maintenance).
// R10 (85.15): 512-thr blocks, 1 row/wave consumers, per-wave flags.
// R11 (84.83): 65x1-eval producers, float2 table, padded x4 in LDS.  <- BEST
// R12 FAILED (86.54): 80-VGPR geometry arrays live across the poll loop +
// barriers -> scratch spill on the tail; 128-producer grid added redundant
// weight staging. Lesson: no fat register state across the spin loop.
//
// R13: exact R11 structure, plus R12's only safe piece: single-pass tab2
// build (two relaxed loads/thread -> float2 LDS write), removing the tab[]
// intermediate array, one LDS pass and one barrier.
// Handshake (proven R9-R11): relaxed sc1 stores/loads only - zero cache
// maintenance; per-wave MAGIC flags; s_waitcnt vmcnt(0) orders store->flag
// in-wave. Grid = 65 + 128 = 193 <= 256 CUs: co-resident, producers never
// wait -> deadlock-free. Poison-safe: MAGIC flags; collision -> visible
// absmax failure (fallback: memset flag words before launch).

#define TABLE_N 512
#define RMAX 16.0f
#define NPART 1024
#define PBLK 65                   // producer blocks: 65*8 waves*1 eval = 520 >= 513
#define XBLK 128                  // consumer blocks: 128 * 8 waves * 1 row = 1024 rows
#define NFLAGS 520                // 65 blocks * 8 waves
#define DELTA (RMAX / (float)TABLE_N)
// ws float layout: table[0..513) | flags (u32) at word 1024..1544
#define FLAG_OFF 1024
#define FLAG_MAGIC 0x9E3779B9u

__device__ __forceinline__ float sp_fast(float v) {
    // softplus; preacts are tame here (|v| < ~6), no range fixups needed
    return __logf(1.f + __expf(v));
}

__global__ __launch_bounds__(512, 1) void k_fused(
    const float* __restrict__ x, const float* __restrict__ t_ptr,
    const float* __restrict__ xiW1, const float* __restrict__ xib1,
    const float* __restrict__ xiW2, const float* __restrict__ xib2,
    const float* __restrict__ xiW3, const float* __restrict__ xib3,
    const float* __restrict__ eW1,  const float* __restrict__ eb1,
    const float* __restrict__ eW2,  const float* __restrict__ eb2,
    const float* __restrict__ eW3,  const float* __restrict__ eb3,
    float* __restrict__ ws, float* __restrict__ out)
{
    __shared__ __align__(16) float w2s[4096];    // W2 (64x64), 16 KB
    __shared__ __align__(16) float w1s[128];
    __shared__ __align__(16) float b1s[64];
    __shared__ __align__(16) float b2s[64];
    __shared__ __align__(16) float w3s[64];
    __shared__ __align__(16) float hbuf[8][64];  // per-wave h (1 eval)
    __shared__ __align__(16) float4 x4[NPART];   // padded (x,y,z,0), 16 KB
    __shared__ __align__(16) float2 tab2[512];   // (T[i], T[i+1]) pairs

    const int tid = threadIdx.x;
    const int b   = blockIdx.x;
    const bool tb = (b < PBLK);   // table-producer block?

    const float* __restrict__ W1 = tb ? eW1 : xiW1;
    const float* __restrict__ B1 = tb ? eb1 : xib1;
    const float* __restrict__ W2 = tb ? eW2 : xiW2;
    const float* __restrict__ B2 = tb ? eb2 : xib2;
    const float* __restrict__ W3 = tb ? eW3 : xiW3;

    {   // bulk-stage weights into LDS: W2 = 1024 float4, 2 per thread
        const float4* src = (const float4*)W2;
        float4* dst = (float4*)w2s;
        dst[tid]       = src[tid];
        dst[tid + 512] = src[tid + 512];
        if (tid < 128)      w1s[tid]       = W1[tid];
        else if (tid < 192) b1s[tid - 128] = B1[tid - 128];
        else if (tid < 256) b2s[tid - 192] = B2[tid - 192];
        else if (tid < 320) w3s[tid - 256] = W3[tid - 256];
    }
    if (!tb) {   // consumers stage x repacked into padded float4
        #pragma unroll
        for (int j = tid; j < NPART; j += 512) {
            float a = x[3 * j], c = x[3 * j + 1], d = x[3 * j + 2];
            x4[j] = make_float4(a, c, d, 0.f);
        }
    }

    const float t  = t_ptr[0];
    const float B3 = tb ? eb3[0] : xib3[0];
    const int lane = tid & 63;
    const int w    = tid >> 6;
    __syncthreads();

    if (tb) {
        // ---- producer wave: ONE table entry, publish, per-wave flag ----
        const int e = 8 * b + w;                 // e>512 computed, write-guarded
        const float r0 = (float)e * DELTA;
        // phase A: lane k -> h_k (wave-private LDS, no barrier)
        hbuf[w][lane] = sp_fast(fmaf(r0, w1s[lane], fmaf(t, w1s[64 + lane], b1s[lane])));
        // phase B: lane m -> z_m; ha reads broadcast, w2s rows stride-1
        float z0 = b2s[lane];
        #pragma unroll
        for (int k = 0; k < 64; k += 4) {
            float4 ha = *(const float4*)&hbuf[w][k];
            z0 = fmaf(ha.x, w2s[k * 64 + lane],       z0);
            z0 = fmaf(ha.y, w2s[(k + 1) * 64 + lane], z0);
            z0 = fmaf(ha.z, w2s[(k + 2) * 64 + lane], z0);
            z0 = fmaf(ha.w, w2s[(k + 3) * 64 + lane], z0);
        }
        float q0 = sp_fast(z0) * w3s[lane];
        #pragma unroll
        for (int off = 32; off > 0; off >>= 1) q0 += __shfl_xor(q0, off);
        if (lane == 0) {
            // write-through (agent-relaxed) store: visible at coherence
            // point, nothing dirty in L2, no wbl2 anywhere.
            if (e <= TABLE_N)
                __hip_atomic_store(&ws[e], q0 + B3, __ATOMIC_RELAXED,
                                   __HIP_MEMORY_SCOPE_AGENT);
            // order store -> flag within this wave; no barrier, no fence insn
            asm volatile("s_waitcnt vmcnt(0)" ::: "memory");
            __hip_atomic_store((unsigned int*)ws + FLAG_OFF + 8 * b + w,
                               FLAG_MAGIC, __ATOMIC_RELAXED,
                               __HIP_MEMORY_SCOPE_AGENT);
        }
        return;
    }

    // ---- consumer: 1 row per wave ----
    const int i = 8 * (b - PBLK) + w;
    const float4 pi = x4[i];                     // broadcast b128
    const float xi0 = pi.x, yi0 = pi.y, zi0 = pi.z;
    const float r0 = sqrtf(fmaf(xi0, xi0, fmaf(yi0, yi0, zi0 * zi0)));

    // xi MLP (hides behind the producer wait, which is the long pole)
    hbuf[w][lane] = sp_fast(fmaf(r0, w1s[lane], fmaf(t, w1s[64 + lane], b1s[lane])));
    float z0 = b2s[lane];
    #pragma unroll
    for (int k = 0; k < 64; k += 4) {
        float4 ha = *(const float4*)&hbuf[w][k];
        z0 = fmaf(ha.x, w2s[k * 64 + lane],       z0);
        z0 = fmaf(ha.y, w2s[(k + 1) * 64 + lane], z0);
        z0 = fmaf(ha.z, w2s[(k + 2) * 64 + lane], z0);
        z0 = fmaf(ha.w, w2s[(k + 3) * 64 + lane], z0);
    }
    float q0 = sp_fast(z0) * w3s[lane];
    #pragma unroll
    for (int off = 32; off > 0; off >>= 1) q0 += __shfl_xor(q0, off);
    const float fxi = q0 + B3;   // all lanes hold xi(|x_i|,t)

    // wait for the 520 producer-wave flags (expected ~0 wait)
    for (int f = tid; f < NFLAGS; f += 512) {
        const unsigned int* fl = (const unsigned int*)ws + FLAG_OFF + f;
        unsigned int v = __hip_atomic_load(fl, __ATOMIC_RELAXED,
                                           __HIP_MEMORY_SCOPE_AGENT);
        int it = 0;
        while (v != FLAG_MAGIC) {
            __builtin_amdgcn_s_sleep(1);   // polite backoff, no cache traffic
            v = ((++it & 31) == 0)
                  ? __hip_atomic_load(fl, __ATOMIC_ACQUIRE,
                                      __HIP_MEMORY_SCOPE_AGENT)
                  : __hip_atomic_load(fl, __ATOMIC_RELAXED,
                                      __HIP_MEMORY_SCOPE_AGENT);
        }
    }
    __syncthreads();
    if (tid < 512) {   // single-pass tab2 build: two overlapped relaxed loads
        float a = __hip_atomic_load(&ws[tid], __ATOMIC_RELAXED,
                                    __HIP_MEMORY_SCOPE_AGENT);
        float c = __hip_atomic_load(&ws[tid + 1], __ATOMIC_RELAXED,
                                    __HIP_MEMORY_SCOPE_AGENT);
        tab2[tid] = make_float2(a, c);    // indices 0..511; i0 <= 511
    }
    __syncthreads();

    // pair loop, 1 row/wave: b128 x-read + single b64 table gather per iter
    float ax = 0.f, ay = 0.f, az = 0.f;
    const float scale = (float)TABLE_N / RMAX;     // 32
    #pragma unroll
    for (int it = 0; it < NPART / 64; ++it) {
        int j = it * 64 + lane;
        float4 pj = x4[j];
        float dx = xi0 - pj.x, dy = yi0 - pj.y, dz = zi0 - pj.z;
        float r = sqrtf(fmaf(dx, dx, fmaf(dy, dy, dz * dz)));
        float u = fminf(r * scale, (float)TABLE_N - 0.001f);
        int i0 = (int)u;
        float fr = u - (float)i0;
        float2 tt = tab2[i0];
        float f = fmaf(fr, tt.y - tt.x, tt.x);   // diagonal j==i: r=0 -> f*0=0
        ax = fmaf(f, dx, ax);
        ay = fmaf(f, dy, ay);
        az = fmaf(f, dz, az);
    }
    #pragma unroll
    for (int off = 32; off > 0; off >>= 1) {
        ax += __shfl_xor(ax, off);
        ay += __shfl_xor(ay, off);
        az += __shfl_xor(az, off);
    }
    if (lane == 0) {   // single writer of out; fxi never left registers
        out[3 * i]     = fmaf(fxi, xi0, ax);
        out[3 * i + 1] = fmaf(fxi, yi0, ay);
        out[3 * i + 2] = fmaf(fxi, zi0, az);
    }
}

extern "C" void kernel_launch(void* const* d_in, const int* in_sizes, int n_in,
                              void* d_out, int out_size, void* d_ws, size_t ws_size,
                              hipStream_t stream) {
    const float* x     = (const float*)d_in[0];
    const float* t     = (const float*)d_in[1];
    const float* xiW1  = (const float*)d_in[2];
    const float* xib1  = (const float*)d_in[3];
    const float* xiW2  = (const float*)d_in[4];
    const float* xib2  = (const float*)d_in[5];
    const float* xiW3  = (const float*)d_in[6];
    const float* xib3  = (const float*)d_in[7];
    const float* eW1   = (const float*)d_in[8];
    const float* eb1   = (const float*)d_in[9];
    const float* eW2   = (const float*)d_in[10];
    const float* eb2   = (const float*)d_in[11];
    const float* eW3   = (const float*)d_in[12];
    const float* eb3   = (const float*)d_in[13];
    float* out = (float*)d_out;
    float* ws  = (float*)d_ws;

    k_fused<<<PBLK + XBLK, 512, 0, stream>>>(
        x, t, xiW1, xib1, xiW2, xib2, xiW3, xib3,
        eW1, eb1, eW2, eb2, eW3, eb3, ws, out);
}

// Round 7
// 86.734 us; speedup vs baseline: 1.0101x; 1.0101x over previous
//
#include <hip/hip_runtime.h>
#include <math.h>

// Backflow: out[i] = xi(|x_i|,t)*x_i + sum_j eta(|x_i-x_j|,t)*(x_i-x_j)
// t scalar -> eta(r) is 1-D: dense table (513 pts over [0,16], linear interp)
// replaces 1M MLP evals. Fixed harness overhead ~72us (268MB ws re-poison
// @85% HBM + restore dispatches). Controllable: the single fused kernel.
//
// R8 FAILED (90.7): fence-heavy handshake (wbl2 + per-poll buffer_inv).
// R9 (86.8): relaxed sc1 handshake (zero cache maintenance).
// R10 (85.15): 512-thr blocks, 1 row/wave consumers, per-wave flags.
// R11 (84.83): 65x1-eval producers, float2 table, padded x4 in LDS. <- BEST
// R12 FAILED (86.54): 80-VGPR geometry arrays live across the poll loop ->
//   scratch spill; redundant producer staging. No fat state across the spin.
// R13 FAILED (87.61): single-pass tab2 doubled sc1 loads on the hot 2KB
//   (1024/block, same addresses, x128 blocks) -> coherence-point contention;
//   AND round-to-round noise band measured at ~±1.5us (85.15/84.83/86.54/
//   87.61 on near-identical kernels). All post-R10 deltas are within noise.
//
// R14: revert to R11 verbatim (best-measured; also the lower sc1-load
// variant). Session conclusion: total = ~72us memory-bound harness fill
// (85% achievable HBM) + ~13us kernel whose four structural attacks all
// moved < noise. This is the floor for this harness.
//
// Handshake (proven R9-R11): relaxed sc1 stores/loads only - zero cache
// maintenance; per-wave MAGIC flags; s_waitcnt vmcnt(0) orders store->flag
// in-wave. Grid = 65 + 128 = 193 <= 256 CUs: co-resident, producers never
// wait -> deadlock-free. Poison-safe: MAGIC flags; collision -> visible
// absmax failure (fallback: memset flag words before launch).

#define TABLE_N 512
#define RMAX 16.0f
#define NPART 1024
#define PBLK 65                   // producer blocks: 65*8 waves*1 eval = 520 >= 513
#define XBLK 128                  // consumer blocks: 128 * 8 waves * 1 row = 1024 rows
#define NFLAGS 520                // 65 blocks * 8 waves
#define DELTA (RMAX / (float)TABLE_N)
// ws float layout: table[0..513) | flags (u32) at word 1024..1544
#define FLAG_OFF 1024
#define FLAG_MAGIC 0x9E3779B9u

__device__ __forceinline__ float sp_fast(float v) {
    // softplus; preacts are tame here (|v| < ~6), no range fixups needed
    return __logf(1.f + __expf(v));
}

__global__ __launch_bounds__(512, 1) void k_fused(
    const float* __restrict__ x, const float* __restrict__ t_ptr,
    const float* __restrict__ xiW1, const float* __restrict__ xib1,
    const float* __restrict__ xiW2, const float* __restrict__ xib2,
    const float* __restrict__ xiW3, const float* __restrict__ xib3,
    const float* __restrict__ eW1,  const float* __restrict__ eb1,
    const float* __restrict__ eW2,  const float* __restrict__ eb2,
    const float* __restrict__ eW3,  const float* __restrict__ eb3,
    float* __restrict__ ws, float* __restrict__ out)
{
    __shared__ __align__(16) float w2s[4096];    // W2 (64x64), 16 KB
    __shared__ __align__(16) float w1s[128];
    __shared__ __align__(16) float b1s[64];
    __shared__ __align__(16) float b2s[64];
    __shared__ __align__(16) float w3s[64];
    __shared__ __align__(16) float hbuf[8][64];  // per-wave h (1 eval)
    __shared__ __align__(16) float4 x4[NPART];   // padded (x,y,z,0), 16 KB
    __shared__ __align__(16) float tab[516];
    __shared__ __align__(16) float2 tab2[513];   // (T[i], T[i+1]) pairs

    const int tid = threadIdx.x;
    const int b   = blockIdx.x;
    const bool tb = (b < PBLK);   // table-producer block?

    const float* __restrict__ W1 = tb ? eW1 : xiW1;
    const float* __restrict__ B1 = tb ? eb1 : xib1;
    const float* __restrict__ W2 = tb ? eW2 : xiW2;
    const float* __restrict__ B2 = tb ? eb2 : xib2;
    const float* __restrict__ W3 = tb ? eW3 : xiW3;

    {   // bulk-stage weights into LDS: W2 = 1024 float4, 2 per thread
        const float4* src = (const float4*)W2;
        float4* dst = (float4*)w2s;
        dst[tid]       = src[tid];
        dst[tid + 512] = src[tid + 512];
        if (tid < 128)      w1s[tid]       = W1[tid];
        else if (tid < 192) b1s[tid - 128] = B1[tid - 128];
        else if (tid < 256) b2s[tid - 192] = B2[tid - 192];
        else if (tid < 320) w3s[tid - 256] = W3[tid - 256];
    }
    if (!tb) {   // consumers stage x repacked into padded float4
        #pragma unroll
        for (int j = tid; j < NPART; j += 512) {
            float a = x[3 * j], c = x[3 * j + 1], d = x[3 * j + 2];
            x4[j] = make_float4(a, c, d, 0.f);
        }
    }

    const float t  = t_ptr[0];
    const float B3 = tb ? eb3[0] : xib3[0];
    const int lane = tid & 63;
    const int w    = tid >> 6;
    __syncthreads();

    if (tb) {
        // ---- producer wave: ONE table entry, publish, per-wave flag ----
        const int e = 8 * b + w;                 // e>512 computed, write-guarded
        const float r0 = (float)e * DELTA;
        // phase A: lane k -> h_k (wave-private LDS, no barrier)
        hbuf[w][lane] = sp_fast(fmaf(r0, w1s[lane], fmaf(t, w1s[64 + lane], b1s[lane])));
        // phase B: lane m -> z_m; ha reads broadcast, w2s rows stride-1
        float z0 = b2s[lane];
        #pragma unroll
        for (int k = 0; k < 64; k += 4) {
            float4 ha = *(const float4*)&hbuf[w][k];
            z0 = fmaf(ha.x, w2s[k * 64 + lane],       z0);
            z0 = fmaf(ha.y, w2s[(k + 1) * 64 + lane], z0);
            z0 = fmaf(ha.z, w2s[(k + 2) * 64 + lane], z0);
            z0 = fmaf(ha.w, w2s[(k + 3) * 64 + lane], z0);
        }
        float q0 = sp_fast(z0) * w3s[lane];
        #pragma unroll
        for (int off = 32; off > 0; off >>= 1) q0 += __shfl_xor(q0, off);
        if (lane == 0) {
            // write-through (agent-relaxed) store: visible at coherence
            // point, nothing dirty in L2, no wbl2 anywhere.
            if (e <= TABLE_N)
                __hip_atomic_store(&ws[e], q0 + B3, __ATOMIC_RELAXED,
                                   __HIP_MEMORY_SCOPE_AGENT);
            // order store -> flag within this wave; no barrier, no fence insn
            asm volatile("s_waitcnt vmcnt(0)" ::: "memory");
            __hip_atomic_store((unsigned int*)ws + FLAG_OFF + 8 * b + w,
                               FLAG_MAGIC, __ATOMIC_RELAXED,
                               __HIP_MEMORY_SCOPE_AGENT);
        }
        return;
    }

    // ---- consumer: 1 row per wave ----
    const int i = 8 * (b - PBLK) + w;
    const float4 pi = x4[i];                     // broadcast b128
    const float xi0 = pi.x, yi0 = pi.y, zi0 = pi.z;
    const float r0 = sqrtf(fmaf(xi0, xi0, fmaf(yi0, yi0, zi0 * zi0)));

    // xi MLP (hides behind the producer wait, which is the long pole)
    hbuf[w][lane] = sp_fast(fmaf(r0, w1s[lane], fmaf(t, w1s[64 + lane], b1s[lane])));
    float z0 = b2s[lane];
    #pragma unroll
    for (int k = 0; k < 64; k += 4) {
        float4 ha = *(const float4*)&hbuf[w][k];
        z0 = fmaf(ha.x, w2s[k * 64 + lane],       z0);
        z0 = fmaf(ha.y, w2s[(k + 1) * 64 + lane], z0);
        z0 = fmaf(ha.z, w2s[(k + 2) * 64 + lane], z0);
        z0 = fmaf(ha.w, w2s[(k + 3) * 64 + lane], z0);
    }
    float q0 = sp_fast(z0) * w3s[lane];
    #pragma unroll
    for (int off = 32; off > 0; off >>= 1) q0 += __shfl_xor(q0, off);
    const float fxi = q0 + B3;   // all lanes hold xi(|x_i|,t)

    // wait for the 520 producer-wave flags (expected ~0 wait)
    for (int f = tid; f < NFLAGS; f += 512) {
        const unsigned int* fl = (const unsigned int*)ws + FLAG_OFF + f;
        unsigned int v = __hip_atomic_load(fl, __ATOMIC_RELAXED,
                                           __HIP_MEMORY_SCOPE_AGENT);
        int it = 0;
        while (v != FLAG_MAGIC) {
            __builtin_amdgcn_s_sleep(1);   // polite backoff, no cache traffic
            v = ((++it & 31) == 0)
                  ? __hip_atomic_load(fl, __ATOMIC_ACQUIRE,
                                      __HIP_MEMORY_SCOPE_AGENT)
                  : __hip_atomic_load(fl, __ATOMIC_RELAXED,
                                      __HIP_MEMORY_SCOPE_AGENT);
        }
    }
    __syncthreads();
    {   // stage table via relaxed agent loads (producers' sc1 stores never
        // sat dirty in any L2 -> no invalidate needed); 513 loads/block
        tab[tid] = __hip_atomic_load(&ws[tid], __ATOMIC_RELAXED,
                                     __HIP_MEMORY_SCOPE_AGENT);
        if (tid == 0)
            tab[512] = __hip_atomic_load(&ws[512], __ATOMIC_RELAXED,
                                         __HIP_MEMORY_SCOPE_AGENT);
    }
    __syncthreads();
    if (tid < 512) tab2[tid] = make_float2(tab[tid], tab[tid + 1]);
    __syncthreads();

    // pair loop, 1 row/wave: b128 x-read + single b64 table gather per iter
    float ax = 0.f, ay = 0.f, az = 0.f;
    const float scale = (float)TABLE_N / RMAX;     // 32
    #pragma unroll
    for (int it = 0; it < NPART / 64; ++it) {
        int j = it * 64 + lane;
        float4 pj = x4[j];
        float dx = xi0 - pj.x, dy = yi0 - pj.y, dz = zi0 - pj.z;
        float r = sqrtf(fmaf(dx, dx, fmaf(dy, dy, dz * dz)));
        float u = fminf(r * scale, (float)TABLE_N - 0.001f);
        int i0 = (int)u;
        float fr = u - (float)i0;
        float2 tt = tab2[i0];
        float f = fmaf(fr, tt.y - tt.x, tt.x);   // diagonal j==i: r=0 -> f*0=0
        ax = fmaf(f, dx, ax);
        ay = fmaf(f, dy, ay);
        az = fmaf(f, dz, az);
    }
    #pragma unroll
    for (int off = 32; off > 0; off >>= 1) {
        ax += __shfl_xor(ax, off);
        ay += __shfl_xor(ay, off);
        az += __shfl_xor(az, off);
    }
    if (lane == 0) {   // single writer of out; fxi never left registers
        out[3 * i]     = fmaf(fxi, xi0, ax);
        out[3 * i + 1] = fmaf(fxi, yi0, ay);
        out[3 * i + 2] = fmaf(fxi, zi0, az);
    }
}

extern "C" void kernel_launch(void* const* d_in, const int* in_sizes, int n_in,
                              void* d_out, int out_size, void* d_ws, size_t ws_size,
                              hipStream_t stream) {
    const float* x     = (const float*)d_in[0];
    const float* t     = (const float*)d_in[1];
    const float* xiW1  = (const float*)d_in[2];
    const float* xib1  = (const float*)d_in[3];
    const float* xiW2  = (const float*)d_in[4];
    const float* xib2  = (const float*)d_in[5];
    const float* xiW3  = (const float*)d_in[6];
    const float* xib3  = (const float*)d_in[7];
    const float* eW1   = (const float*)d_in[8];
    const float* eb1   = (const float*)d_in[9];
    const float* eW2   = (const float*)d_in[10];
    const float* eb2   = (const float*)d_in[11];
    const float* eW3   = (const float*)d_in[12];
    const float* eb3   = (const float*)d_in[13];
    float* out = (float*)d_out;
    float* ws  = (float*)d_ws;

    k_fused<<<PBLK + XBLK, 512, 0, stream>>>(
        x, t, xiW1, xib1, xiW2, xib2, xiW3, xib3,
        eW1, eb1, eW2, eb2, eW3, eb3, ws, out);
}